// Round 2
// baseline (651.897 us; speedup 1.0000x reference)
//
#include <hip/hip_runtime.h>
#include <stdint.h>
#include <math.h>

// B=4, T=2048, D=2048, HEADS=16.  Inputs/outputs fp32; internal compute bf16
// MFMA with fp32 accumulation (no fp32-input MFMA on CDNA4).
//
// Pipeline:
//  0: cast x, w_qk, w_dense fp32 -> bf16 workspace copies (xb, wqkb, wdb)
//  A: kv^T GEMM  : C[e,bt] = sum_d wqkb[e,d] * xb[bt,d]  -> k0T (2048x8192), vT (2048x8192)
//  T: transpose  : Vn[bt,d] = vT[d,bt]
//  B: s[b,i,j] = scale * sum_m k0T[i, b*2048+m] * Vn[b*2048+j, m]  -> sb (4,2048,2048)
//  S: softmax rows of sb (in place)
//  C: q[b,i,d] = sum_t sb[b,i,t] * vT[d, b*2048+t]       -> qb (4,2048,2048)
//  D: out[bt',e] = sum_d qb[rowmap(bt'), d] * wdb[e,d] + bias[e]  -> d_out (fp32)
//     rowmap folds the reference's swapaxes/reshape/transpose permutation (row-only).
//
// Memory plan: Vn + sb live inside d_out (2 x 32MB bf16 = 64MB = d_out size;
// both dead before stage D rewrites d_out). qb aliases xb (dead after A).
// Peak d_ws use = 126 MB.

typedef __bf16 bf16x8 __attribute__((ext_vector_type(8)));
typedef float  f32x4  __attribute__((ext_vector_type(4)));

__device__ __forceinline__ float bf2f(uint16_t u) {
  union { uint32_t i; float f; } c; c.i = ((uint32_t)u) << 16; return c.f;
}
__device__ __forceinline__ uint16_t f2bf(float f) {
  union { float f; uint32_t i; } c; c.f = f;
  uint32_t i = c.i;
  return (uint16_t)((i + 0x7fffu + ((i >> 16) & 1u)) >> 16);  // RNE
}

__device__ __forceinline__ void gll16(const void* g, void* l) {
  // async global->LDS, 16B/lane; LDS dest = wave-uniform base + lane*16
  __builtin_amdgcn_global_load_lds((const __attribute__((address_space(1))) void*)g,
                                   (__attribute__((address_space(3))) void*)l,
                                   16, 0, 0);
}

// ---- fp32 -> bf16 cast, 4 elems/thread --------------------------------------
__global__ __launch_bounds__(256) void k_cast(const float* __restrict__ src,
                                              uint16_t* __restrict__ dst, int n4) {
  int i = blockIdx.x * 256 + threadIdx.x;
  if (i >= n4) return;
  float4 v = reinterpret_cast<const float4*>(src)[i];
  ushort4 o;
  o.x = f2bf(v.x); o.y = f2bf(v.y); o.z = f2bf(v.z); o.w = f2bf(v.w);
  reinterpret_cast<ushort4*>(dst)[i] = o;
}

// ---- shared 128x128 GEMM core (BK=32, 256 thr = 4 waves in 2x2 of 64x64) ----
__device__ __forceinline__ void gemm_core(
    const uint16_t* a0, const uint16_t* a1,
    const uint16_t* b0, const uint16_t* b1,
    uint16_t* As, uint16_t* Bs, int K, f32x4 acc[4][4])
{
  const int tid = threadIdx.x;
  const int w = tid >> 6, l = tid & 63;
  const int wm = (w >> 1) * 64, wn = (w & 1) * 64;
  const int frow = l & 15, fk = (l >> 4) * 8;
  uint16_t* ldsA0 = As + (w * 64) * 8;        // wave-uniform bases
  uint16_t* ldsA1 = As + (256 + w * 64) * 8;
  uint16_t* ldsB0 = Bs + (w * 64) * 8;
  uint16_t* ldsB1 = Bs + (256 + w * 64) * 8;
  for (int kb = 0; kb < K; kb += 32) {
    __syncthreads();                 // prev compute done before LDS overwrite
    gll16(a0, ldsA0);
    gll16(a1, ldsA1);
    gll16(b0, ldsB0);
    gll16(b1, ldsB1);
    a0 += 32; a1 += 32; b0 += 32; b1 += 32;
    __syncthreads();                 // drains vmcnt (loads landed)
    bf16x8 af[4], bfv[4];
#pragma unroll
    for (int mi = 0; mi < 4; ++mi)
      af[mi] = *reinterpret_cast<const bf16x8*>(&As[(wm + mi * 16 + frow) * 32 + fk]);
#pragma unroll
    for (int ni = 0; ni < 4; ++ni)
      bfv[ni] = *reinterpret_cast<const bf16x8*>(&Bs[(wn + ni * 16 + frow) * 32 + fk]);
#pragma unroll
    for (int mi = 0; mi < 4; ++mi)
#pragma unroll
      for (int ni = 0; ni < 4; ++ni)
        acc[mi][ni] = __builtin_amdgcn_mfma_f32_16x16x32_bf16(af[mi], bfv[ni], acc[mi][ni], 0, 0, 0);
  }
}

// ---- stage A: kv^T, split-store into k0T / vT --------------------------------
__global__ __launch_bounds__(256) void k_gemm_kv(
    const uint16_t* __restrict__ W,    // wqkb 4096x2048 (row e, k-contig)
    const uint16_t* __restrict__ X,    // xb   8192x2048 (row bt, k-contig)
    uint16_t* __restrict__ k0T,        // 2048x8192
    uint16_t* __restrict__ vT)         // 2048x8192
{
  __shared__ uint16_t As[4096], Bs[4096];
  const int tid = threadIdx.x;
  const int bm = blockIdx.y, bn = blockIdx.x;
  const int r = tid >> 2, ko = (tid & 3) * 8;
  const uint16_t* a0 = W + (size_t)(bm * 128 + r) * 2048 + ko;
  const uint16_t* a1 = a0 + (size_t)64 * 2048;
  const uint16_t* b0 = X + (size_t)(bn * 128 + r) * 2048 + ko;
  const uint16_t* b1 = b0 + (size_t)64 * 2048;
  f32x4 acc[4][4];
#pragma unroll
  for (int i = 0; i < 4; ++i)
#pragma unroll
    for (int j = 0; j < 4; ++j) acc[i][j] = (f32x4){0.f, 0.f, 0.f, 0.f};
  gemm_core(a0, a1, b0, b1, As, Bs, 2048, acc);
  const int w = tid >> 6, l = tid & 63;
  const int wm = (w >> 1) * 64, wn = (w & 1) * 64;
  const int cr = (l >> 4) * 4, cc = l & 15;
#pragma unroll
  for (int mi = 0; mi < 4; ++mi)
#pragma unroll
    for (int ni = 0; ni < 4; ++ni)
#pragma unroll
      for (int g = 0; g < 4; ++g) {
        int e  = bm * 128 + wm + mi * 16 + cr + g;
        int bt = bn * 128 + wn + ni * 16 + cc;
        uint16_t v = f2bf(acc[mi][ni][g]);
        if (e < 2048) k0T[(size_t)e * 8192 + bt] = v;
        else          vT[(size_t)(e - 2048) * 8192 + bt] = v;
      }
}

// ---- generic batched A@B^T (both K-contig), scaled bf16 store ----------------
__global__ __launch_bounds__(256) void k_gemm_bt(
    const uint16_t* __restrict__ A, int lda, long sA,
    const uint16_t* __restrict__ B, int ldb, long sB,
    uint16_t* __restrict__ C, int ldc, long sC,
    int K, float scale)
{
  __shared__ uint16_t As[4096], Bs[4096];
  const int z = blockIdx.z;
  A += (size_t)z * sA; B += (size_t)z * sB; C += (size_t)z * sC;
  const int tid = threadIdx.x;
  const int bm = blockIdx.y, bn = blockIdx.x;
  const int r = tid >> 2, ko = (tid & 3) * 8;
  const uint16_t* a0 = A + (size_t)(bm * 128 + r) * lda + ko;
  const uint16_t* a1 = a0 + (size_t)64 * lda;
  const uint16_t* b0 = B + (size_t)(bn * 128 + r) * ldb + ko;
  const uint16_t* b1 = b0 + (size_t)64 * ldb;
  f32x4 acc[4][4];
#pragma unroll
  for (int i = 0; i < 4; ++i)
#pragma unroll
    for (int j = 0; j < 4; ++j) acc[i][j] = (f32x4){0.f, 0.f, 0.f, 0.f};
  gemm_core(a0, a1, b0, b1, As, Bs, K, acc);
  const int w = tid >> 6, l = tid & 63;
  const int wm = (w >> 1) * 64, wn = (w & 1) * 64;
  const int cr = (l >> 4) * 4, cc = l & 15;
#pragma unroll
  for (int mi = 0; mi < 4; ++mi)
#pragma unroll
    for (int ni = 0; ni < 4; ++ni)
#pragma unroll
      for (int g = 0; g < 4; ++g) {
        int grow = bm * 128 + wm + mi * 16 + cr + g;
        int gcol = bn * 128 + wn + ni * 16 + cc;
        C[(size_t)grow * ldc + gcol] = f2bf(acc[mi][ni][g] * scale);
      }
}

// ---- stage D: permuted-A GEMM + fp32 bias/store into d_out -------------------
__device__ __forceinline__ size_t qrow_off(int rr) {
  // rr = b'*2048 + t' ; q row = (b_i, i) with b_i=(t'>>4)&3, i=(t'&15)*128+b'*32+(t'>>6)
  int bp = rr >> 11, tp = rr & 2047;
  int bi = (tp >> 4) & 3;
  int i  = (tp & 15) * 128 + bp * 32 + (tp >> 6);
  return ((size_t)bi * 2048 + (size_t)i) * 2048;
}

__global__ __launch_bounds__(256) void k_gemm_out(
    const uint16_t* __restrict__ Q,     // qb (4,2048,2048) bf16
    const uint16_t* __restrict__ W,     // wdb 2048x2048 bf16 (row e, k-contig)
    const float*    __restrict__ bias,  // b_dense fp32 (2048)
    float*          __restrict__ Out)   // d_out 8192x2048 fp32
{
  __shared__ uint16_t As[4096], Bs[4096];
  const int tid = threadIdx.x;
  const int bm = blockIdx.y, bn = blockIdx.x;
  const int r = tid >> 2, ko = (tid & 3) * 8;
  const uint16_t* a0 = Q + qrow_off(bm * 128 + r) + ko;
  const uint16_t* a1 = Q + qrow_off(bm * 128 + r + 64) + ko;
  const uint16_t* b0 = W + (size_t)(bn * 128 + r) * 2048 + ko;
  const uint16_t* b1 = b0 + (size_t)64 * 2048;
  f32x4 acc[4][4];
#pragma unroll
  for (int i = 0; i < 4; ++i)
#pragma unroll
    for (int j = 0; j < 4; ++j) acc[i][j] = (f32x4){0.f, 0.f, 0.f, 0.f};
  gemm_core(a0, a1, b0, b1, As, Bs, 2048, acc);
  const int w = tid >> 6, l = tid & 63;
  const int wm = (w >> 1) * 64, wn = (w & 1) * 64;
  const int cr = (l >> 4) * 4, cc = l & 15;
#pragma unroll
  for (int mi = 0; mi < 4; ++mi)
#pragma unroll
    for (int ni = 0; ni < 4; ++ni)
#pragma unroll
      for (int g = 0; g < 4; ++g) {
        int grow = bm * 128 + wm + mi * 16 + cr + g;
        int gcol = bn * 128 + wn + ni * 16 + cc;
        Out[(size_t)grow * 2048 + gcol] = acc[mi][ni][g] + bias[gcol];
      }
}

// ---- transpose vT (2048x8192) -> Vn (8192x2048) ------------------------------
__global__ __launch_bounds__(256) void k_transpose(
    const uint16_t* __restrict__ src, uint16_t* __restrict__ dst)
{
  __shared__ uint16_t tile[64][65];
  const int tid = threadIdx.x;
  const int bx = blockIdx.x;   // src col tile (8192/64 = 128)
  const int by = blockIdx.y;   // src row tile (2048/64 = 32)
  const int cu = tid & 31, r0 = tid >> 5;
#pragma unroll
  for (int p = 0; p < 8; ++p) {
    int r = p * 8 + r0;
    uint32_t v = *reinterpret_cast<const uint32_t*>(
        &src[(size_t)(by * 64 + r) * 8192 + bx * 64 + cu * 2]);
    tile[r][cu * 2]     = (uint16_t)(v & 0xffffu);
    tile[r][cu * 2 + 1] = (uint16_t)(v >> 16);
  }
  __syncthreads();
#pragma unroll
  for (int p = 0; p < 8; ++p) {
    int r = p * 8 + r0;                    // dst row within tile = src col
    uint32_t lo = tile[cu * 2][r], hi = tile[cu * 2 + 1][r];
    *reinterpret_cast<uint32_t*>(
        &dst[(size_t)(bx * 64 + r) * 2048 + by * 64 + cu * 2]) = lo | (hi << 16);
  }
}

// ---- row softmax (bf16 in place), 1 block per row of 2048 --------------------
__global__ __launch_bounds__(256) void k_softmax(uint16_t* __restrict__ s)
{
  uint16_t* p = s + (size_t)blockIdx.x * 2048;
  const int tid = threadIdx.x;
  uint4 raw = reinterpret_cast<const uint4*>(p)[tid];
  uint32_t u[4] = {raw.x, raw.y, raw.z, raw.w};
  float x[8];
#pragma unroll
  for (int i = 0; i < 4; ++i) {
    x[2 * i]     = bf2f((uint16_t)(u[i] & 0xffffu));
    x[2 * i + 1] = bf2f((uint16_t)(u[i] >> 16));
  }
  float m = x[0];
#pragma unroll
  for (int i = 1; i < 8; ++i) m = fmaxf(m, x[i]);
#pragma unroll
  for (int o = 32; o; o >>= 1) m = fmaxf(m, __shfl_xor(m, o, 64));
  __shared__ float redm[4], reds[4];
  if ((tid & 63) == 0) redm[tid >> 6] = m;
  __syncthreads();
  m = fmaxf(fmaxf(redm[0], redm[1]), fmaxf(redm[2], redm[3]));
  float sum = 0.f;
#pragma unroll
  for (int i = 0; i < 8; ++i) { x[i] = __expf(x[i] - m); sum += x[i]; }
#pragma unroll
  for (int o = 32; o; o >>= 1) sum += __shfl_xor(sum, o, 64);
  if ((tid & 63) == 0) reds[tid >> 6] = sum;
  __syncthreads();
  sum = reds[0] + reds[1] + reds[2] + reds[3];
  float inv = 1.0f / sum;
  uint32_t ou[4];
#pragma unroll
  for (int i = 0; i < 4; ++i) {
    uint32_t lo = f2bf(x[2 * i] * inv);
    uint32_t hi = f2bf(x[2 * i + 1] * inv);
    ou[i] = lo | (hi << 16);
  }
  reinterpret_cast<uint4*>(p)[tid] = make_uint4(ou[0], ou[1], ou[2], ou[3]);
}

// ------------------------------------------------------------------------------
extern "C" void kernel_launch(void* const* d_in, const int* in_sizes, int n_in,
                              void* d_out, int out_size, void* d_ws, size_t ws_size,
                              hipStream_t stream) {
  const float* x       = (const float*)d_in[0];   // (4,2048,2048) fp32
  const float* w_qk    = (const float*)d_in[1];   // (4096,2048)   fp32
  const float* w_dense = (const float*)d_in[2];   // (2048,2048)   fp32
  const float* b_dense = (const float*)d_in[3];   // (2048,)       fp32
  float* out = (float*)d_out;                     // (4,2048,2048) fp32

  const size_t NX = 4ull * 2048 * 2048;           // 16,777,216
  const size_t NW = 4096ull * 2048;               //  8,388,608
  const size_t ND = 2048ull * 2048;               //  4,194,304

  // d_ws layout (bf16): xb | wqkb | wdb | k0T | vT   (126 MB peak)
  uint16_t* xb   = (uint16_t*)d_ws;       // 8192x2048
  uint16_t* wqkb = xb + NX;               // 4096x2048
  uint16_t* wdb  = wqkb + NW;             // 2048x2048
  uint16_t* k0T  = wdb + ND;              // 2048x8192
  uint16_t* vT   = k0T + NX;              // 2048x8192
  uint16_t* qb   = xb;                    // alias: xb dead after stage A
  // d_out doubles as bf16 scratch (exactly 2 x 32MB; dead before stage D):
  uint16_t* Vn   = (uint16_t*)d_out;      // 8192x2048
  uint16_t* sb   = Vn + NX;               // (4,2048,2048)

  const float scale = (float)(1.0 / sqrt(0.5 * 2048.0 * 2047.0));

  // 0: fp32 -> bf16 casts
  k_cast<<<dim3((int)(NX / 4 / 256)), 256, 0, stream>>>(x, xb, (int)(NX / 4));
  k_cast<<<dim3((int)(NW / 4 / 256)), 256, 0, stream>>>(w_qk, wqkb, (int)(NW / 4));
  k_cast<<<dim3((int)(ND / 4 / 256)), 256, 0, stream>>>(w_dense, wdb, (int)(ND / 4));

  // A: kv^T  (M=4096 e, N=8192 bt, K=2048)
  k_gemm_kv<<<dim3(64, 32), 256, 0, stream>>>(wqkb, xb, k0T, vT);
  // T: vT -> Vn
  k_transpose<<<dim3(128, 32), 256, 0, stream>>>(vT, Vn);
  // B: s = scale * k0T @ Vn^T   (per batch 2048^3)
  k_gemm_bt<<<dim3(16, 16, 4), 256, 0, stream>>>(
      k0T, 8192, 2048L, Vn, 2048, 2048L * 2048L, sb, 2048, 2048L * 2048L, 2048, scale);
  // S: softmax rows
  k_softmax<<<dim3(8192), 256, 0, stream>>>(sb);
  // C: q = a @ vT^T             (per batch 2048^3)
  k_gemm_bt<<<dim3(16, 16, 4), 256, 0, stream>>>(
      sb, 2048, 2048L * 2048L, vT, 8192, 2048L, qb, 2048, 2048L * 2048L, 2048, 1.0f);
  // D: out = perm(q) @ w_dense^T + bias  (M=8192, N=2048, K=2048) -> fp32
  k_gemm_out<<<dim3(16, 64), 256, 0, stream>>>(qb, wdb, b_dense, out);
}

// Round 3
// 575.888 us; speedup vs baseline: 1.1320x; 1.1320x over previous
//
#include <hip/hip_runtime.h>
#include <stdint.h>
#include <math.h>

// B=4, T=2048, D=2048, HEADS=16.  Inputs/outputs fp32; internal compute bf16
// MFMA with fp32 accumulation (no fp32-input MFMA on CDNA4).
//
// Pipeline:
//  0: fused cast x|w_qk|w_dense fp32 -> bf16 (xb|wqkb|wdb contiguous in ws)
//  A: kv^T GEMM  : C[e,bt] = sum_d wqkb[e,d] * xb[bt,d]  -> k0T (2048x8192), vT (2048x8192)
//  T: transpose  : Vn[bt,d] = vT[d,bt]
//  B: s[b,i,j] = scale * sum_m k0T[i, b*2048+m] * Vn[b*2048+j, m]  -> sb (4,2048,2048)
//  S: softmax rows of sb (in place)
//  C: q[b,i,d] = sum_t sb[b,i,t] * vT[d, b*2048+t]       -> qb (4,2048,2048)
//  D: out[bt',e] = sum_d qb[rowmap(bt'), d] * wdb[e,d] + bias[e]  -> d_out (fp32)
//
// GEMM core: 128x128 block tile, BK=64 (one barrier-pair per 64-K vs 32-K
// before — attacks the vmcnt(0) barrier-drain stall), 4 waves in 2x2 of
// 64x64, 16x16x32 bf16 MFMA.  LDS rows are 128B at BK=64 (bank-aligned), so
// staging XORs the k-chunk position by (row&7); frag reads mirror the XOR.
// Memory plan: Vn + sb live inside d_out (dead before stage D); qb aliases xb.

typedef __bf16 bf16x8 __attribute__((ext_vector_type(8)));
typedef float  f32x4  __attribute__((ext_vector_type(4)));

__device__ __forceinline__ float bf2f(uint16_t u) {
  union { uint32_t i; float f; } c; c.i = ((uint32_t)u) << 16; return c.f;
}
__device__ __forceinline__ uint16_t f2bf(float f) {
  union { float f; uint32_t i; } c; c.f = f;
  uint32_t i = c.i;
  return (uint16_t)((i + 0x7fffu + ((i >> 16) & 1u)) >> 16);  // RNE
}

__device__ __forceinline__ void gll16(const void* g, void* l) {
  __builtin_amdgcn_global_load_lds((const __attribute__((address_space(1))) void*)g,
                                   (__attribute__((address_space(3))) void*)l,
                                   16, 0, 0);
}

// ---- fused fp32 -> bf16 cast over x|w_qk|w_dense -----------------------------
#define NX4 4194304u   // (4*2048*2048)/4
#define NW4 2097152u   // (4096*2048)/4
#define ND4 1048576u   // (2048*2048)/4
__global__ __launch_bounds__(256) void k_cast_all(
    const float* __restrict__ x, const float* __restrict__ wqk,
    const float* __restrict__ wd, uint16_t* __restrict__ dst) {
  uint32_t i = blockIdx.x * 256 + threadIdx.x;
  float4 v;
  if (i < NX4)            v = reinterpret_cast<const float4*>(x)[i];
  else if (i < NX4 + NW4) v = reinterpret_cast<const float4*>(wqk)[i - NX4];
  else                    v = reinterpret_cast<const float4*>(wd)[i - NX4 - NW4];
  ushort4 o;
  o.x = f2bf(v.x); o.y = f2bf(v.y); o.z = f2bf(v.z); o.w = f2bf(v.w);
  reinterpret_cast<ushort4*>(dst)[i] = o;
}

// ---- shared 128x128 GEMM core, BK=64 ----------------------------------------
// aC/bC: per-thread global ptrs for 4 staging chunks each (chunk c = tile rows
// c*32 + (tid>>3), k-offset ((tid&7) ^ ((tid>>3)&7))*8).  Advanced 64/K-step.
__device__ __forceinline__ void gemm_core(
    const uint16_t* a0, const uint16_t* a1, const uint16_t* a2, const uint16_t* a3,
    const uint16_t* b0, const uint16_t* b1, const uint16_t* b2, const uint16_t* b3,
    uint16_t* As, uint16_t* Bs, int K, f32x4 acc[4][4])
{
  const int tid = threadIdx.x;
  const int w = tid >> 6, l = tid & 63;
  const int wm = (w >> 1) * 64, wn = (w & 1) * 64;
  const int frow = l & 15, fkc = l >> 4;        // fragment row / k-chunk (0..3)
  const int xr = frow & 7;                      // XOR key (row&7)
  // per-h frag element offsets within a 64-elem row (constant across K loop)
  const int off0 = ((0 * 4 + fkc) ^ xr) * 8;
  const int off1 = ((1 * 4 + fkc) ^ xr) * 8;
  uint16_t* lA0 = As + 0 * 2048 + w * 512;      // wave-uniform LDS bases
  uint16_t* lA1 = As + 1 * 2048 + w * 512;
  uint16_t* lA2 = As + 2 * 2048 + w * 512;
  uint16_t* lA3 = As + 3 * 2048 + w * 512;
  uint16_t* lB0 = Bs + 0 * 2048 + w * 512;
  uint16_t* lB1 = Bs + 1 * 2048 + w * 512;
  uint16_t* lB2 = Bs + 2 * 2048 + w * 512;
  uint16_t* lB3 = Bs + 3 * 2048 + w * 512;
  for (int kb = 0; kb < K; kb += 64) {
    __syncthreads();                 // prev compute done before LDS overwrite
    gll16(a0, lA0); gll16(a1, lA1); gll16(a2, lA2); gll16(a3, lA3);
    gll16(b0, lB0); gll16(b1, lB1); gll16(b2, lB2); gll16(b3, lB3);
    a0 += 64; a1 += 64; a2 += 64; a3 += 64;
    b0 += 64; b1 += 64; b2 += 64; b3 += 64;
    __syncthreads();                 // drains vmcnt (loads landed)
#pragma unroll
    for (int h = 0; h < 2; ++h) {
      const int off = h ? off1 : off0;
      bf16x8 af[4], bfv[4];
#pragma unroll
      for (int mi = 0; mi < 4; ++mi)
        af[mi] = *reinterpret_cast<const bf16x8*>(&As[(wm + mi * 16 + frow) * 64 + off]);
#pragma unroll
      for (int ni = 0; ni < 4; ++ni)
        bfv[ni] = *reinterpret_cast<const bf16x8*>(&Bs[(wn + ni * 16 + frow) * 64 + off]);
#pragma unroll
      for (int mi = 0; mi < 4; ++mi)
#pragma unroll
        for (int ni = 0; ni < 4; ++ni)
          acc[mi][ni] = __builtin_amdgcn_mfma_f32_16x16x32_bf16(af[mi], bfv[ni], acc[mi][ni], 0, 0, 0);
    }
  }
}

// staging-pointer helper: chunk c row/k-offset for plain (non-permuted) operand
__device__ __forceinline__ const uint16_t* stage_ptr(
    const uint16_t* base, int tile_row0, int c, int lda) {
  const int tid = threadIdx.x;
  const int r3 = tid >> 3;
  const int ko = (((tid & 7) ^ (r3 & 7)) * 8);
  return base + (size_t)(tile_row0 + c * 32 + r3) * lda + ko;
}

// ---- stage A: kv^T, block-uniform split-store into k0T / vT ------------------
__global__ __launch_bounds__(256) void k_gemm_kv(
    const uint16_t* __restrict__ W,    // wqkb 4096x2048
    const uint16_t* __restrict__ X,    // xb   8192x2048
    uint16_t* __restrict__ k0T,        // 2048x8192
    uint16_t* __restrict__ vT)         // 2048x8192
{
  __shared__ uint16_t As[8192], Bs[8192];
  const int bm = blockIdx.y, bn = blockIdx.x;
  f32x4 acc[4][4];
#pragma unroll
  for (int i = 0; i < 4; ++i)
#pragma unroll
    for (int j = 0; j < 4; ++j) acc[i][j] = (f32x4){0.f, 0.f, 0.f, 0.f};
  gemm_core(stage_ptr(W, bm * 128, 0, 2048), stage_ptr(W, bm * 128, 1, 2048),
            stage_ptr(W, bm * 128, 2, 2048), stage_ptr(W, bm * 128, 3, 2048),
            stage_ptr(X, bn * 128, 0, 2048), stage_ptr(X, bn * 128, 1, 2048),
            stage_ptr(X, bn * 128, 2, 2048), stage_ptr(X, bn * 128, 3, 2048),
            As, Bs, 2048, acc);
  const int tid = threadIdx.x;
  const int w = tid >> 6, l = tid & 63;
  const int wm = (w >> 1) * 64, wn = (w & 1) * 64;
  const int cr = (l >> 4) * 4, cc = l & 15;
  // block-uniform destination (rows bm*128..+127 are entirely k0 or entirely v)
  uint16_t* Cb = (bm < 16) ? (k0T + (size_t)bm * 128 * 8192)
                           : (vT + (size_t)(bm - 16) * 128 * 8192);
#pragma unroll
  for (int mi = 0; mi < 4; ++mi)
#pragma unroll
    for (int ni = 0; ni < 4; ++ni)
#pragma unroll
      for (int g = 0; g < 4; ++g) {
        int lr = wm + mi * 16 + cr + g;
        int bt = bn * 128 + wn + ni * 16 + cc;
        Cb[(size_t)lr * 8192 + bt] = f2bf(acc[mi][ni][g]);
      }
}

// ---- generic batched A@B^T (both K-contig), scaled bf16 store ----------------
__global__ __launch_bounds__(256) void k_gemm_bt(
    const uint16_t* __restrict__ A, int lda, long sA,
    const uint16_t* __restrict__ B, int ldb, long sB,
    uint16_t* __restrict__ C, int ldc, long sC,
    int K, float scale)
{
  __shared__ uint16_t As[8192], Bs[8192];
  const int z = blockIdx.z;
  A += (size_t)z * sA; B += (size_t)z * sB; C += (size_t)z * sC;
  const int bm = blockIdx.y, bn = blockIdx.x;
  f32x4 acc[4][4];
#pragma unroll
  for (int i = 0; i < 4; ++i)
#pragma unroll
    for (int j = 0; j < 4; ++j) acc[i][j] = (f32x4){0.f, 0.f, 0.f, 0.f};
  gemm_core(stage_ptr(A, bm * 128, 0, lda), stage_ptr(A, bm * 128, 1, lda),
            stage_ptr(A, bm * 128, 2, lda), stage_ptr(A, bm * 128, 3, lda),
            stage_ptr(B, bn * 128, 0, ldb), stage_ptr(B, bn * 128, 1, ldb),
            stage_ptr(B, bn * 128, 2, ldb), stage_ptr(B, bn * 128, 3, ldb),
            As, Bs, K, acc);
  const int tid = threadIdx.x;
  const int w = tid >> 6, l = tid & 63;
  const int wm = (w >> 1) * 64, wn = (w & 1) * 64;
  const int cr = (l >> 4) * 4, cc = l & 15;
#pragma unroll
  for (int mi = 0; mi < 4; ++mi)
#pragma unroll
    for (int ni = 0; ni < 4; ++ni)
#pragma unroll
      for (int g = 0; g < 4; ++g) {
        int grow = bm * 128 + wm + mi * 16 + cr + g;
        int gcol = bn * 128 + wn + ni * 16 + cc;
        C[(size_t)grow * ldc + gcol] = f2bf(acc[mi][ni][g] * scale);
      }
}

// ---- stage D: permuted-A GEMM + fp32 bias/store into d_out -------------------
__device__ __forceinline__ size_t qrow_off(int rr) {
  // rr = b'*2048 + t' ; q row = (b_i, i), b_i=(t'>>4)&3, i=(t'&15)*128+b'*32+(t'>>6)
  int bp = rr >> 11, tp = rr & 2047;
  int bi = (tp >> 4) & 3;
  int i  = (tp & 15) * 128 + bp * 32 + (tp >> 6);
  return ((size_t)bi * 2048 + (size_t)i) * 2048;
}

__global__ __launch_bounds__(256) void k_gemm_out(
    const uint16_t* __restrict__ Q,     // qb (4,2048,2048) bf16
    const uint16_t* __restrict__ W,     // wdb 2048x2048 bf16
    const float*    __restrict__ bias,  // b_dense fp32 (2048)
    float*          __restrict__ Out)   // d_out 8192x2048 fp32
{
  __shared__ uint16_t As[8192], Bs[8192];
  const int tid = threadIdx.x;
  const int bm = blockIdx.y, bn = blockIdx.x;
  const int r3 = tid >> 3;
  const int ko = (((tid & 7) ^ (r3 & 7)) * 8);
  const uint16_t* a0 = Q + qrow_off(bm * 128 + 0 * 32 + r3) + ko;
  const uint16_t* a1 = Q + qrow_off(bm * 128 + 1 * 32 + r3) + ko;
  const uint16_t* a2 = Q + qrow_off(bm * 128 + 2 * 32 + r3) + ko;
  const uint16_t* a3 = Q + qrow_off(bm * 128 + 3 * 32 + r3) + ko;
  f32x4 acc[4][4];
#pragma unroll
  for (int i = 0; i < 4; ++i)
#pragma unroll
    for (int j = 0; j < 4; ++j) acc[i][j] = (f32x4){0.f, 0.f, 0.f, 0.f};
  gemm_core(a0, a1, a2, a3,
            stage_ptr(W, bn * 128, 0, 2048), stage_ptr(W, bn * 128, 1, 2048),
            stage_ptr(W, bn * 128, 2, 2048), stage_ptr(W, bn * 128, 3, 2048),
            As, Bs, 2048, acc);
  const int w = tid >> 6, l = tid & 63;
  const int wm = (w >> 1) * 64, wn = (w & 1) * 64;
  const int cr = (l >> 4) * 4, cc = l & 15;
#pragma unroll
  for (int mi = 0; mi < 4; ++mi)
#pragma unroll
    for (int ni = 0; ni < 4; ++ni)
#pragma unroll
      for (int g = 0; g < 4; ++g) {
        int grow = bm * 128 + wm + mi * 16 + cr + g;
        int gcol = bn * 128 + wn + ni * 16 + cc;
        Out[(size_t)grow * 2048 + gcol] = acc[mi][ni][g] + bias[gcol];
      }
}

// ---- transpose vT (2048x8192) -> Vn (8192x2048) ------------------------------
__global__ __launch_bounds__(256) void k_transpose(
    const uint16_t* __restrict__ src, uint16_t* __restrict__ dst)
{
  __shared__ uint16_t tile[64][65];
  const int tid = threadIdx.x;
  const int bx = blockIdx.x;   // src col tile (8192/64)
  const int by = blockIdx.y;   // src row tile (2048/64)
  const int cu = tid & 31, r0 = tid >> 5;
#pragma unroll
  for (int p = 0; p < 8; ++p) {
    int r = p * 8 + r0;
    uint32_t v = *reinterpret_cast<const uint32_t*>(
        &src[(size_t)(by * 64 + r) * 8192 + bx * 64 + cu * 2]);
    tile[r][cu * 2]     = (uint16_t)(v & 0xffffu);
    tile[r][cu * 2 + 1] = (uint16_t)(v >> 16);
  }
  __syncthreads();
#pragma unroll
  for (int p = 0; p < 8; ++p) {
    int r = p * 8 + r0;
    uint32_t lo = tile[cu * 2][r], hi = tile[cu * 2 + 1][r];
    *reinterpret_cast<uint32_t*>(
        &dst[(size_t)(bx * 64 + r) * 2048 + by * 64 + cu * 2]) = lo | (hi << 16);
  }
}

// ---- row softmax (bf16 in place), 1 block per row of 2048 --------------------
__global__ __launch_bounds__(256) void k_softmax(uint16_t* __restrict__ s)
{
  uint16_t* p = s + (size_t)blockIdx.x * 2048;
  const int tid = threadIdx.x;
  uint4 raw = reinterpret_cast<const uint4*>(p)[tid];
  uint32_t u[4] = {raw.x, raw.y, raw.z, raw.w};
  float x[8];
#pragma unroll
  for (int i = 0; i < 4; ++i) {
    x[2 * i]     = bf2f((uint16_t)(u[i] & 0xffffu));
    x[2 * i + 1] = bf2f((uint16_t)(u[i] >> 16));
  }
  float m = x[0];
#pragma unroll
  for (int i = 1; i < 8; ++i) m = fmaxf(m, x[i]);
#pragma unroll
  for (int o = 32; o; o >>= 1) m = fmaxf(m, __shfl_xor(m, o, 64));
  __shared__ float redm[4], reds[4];
  if ((tid & 63) == 0) redm[tid >> 6] = m;
  __syncthreads();
  m = fmaxf(fmaxf(redm[0], redm[1]), fmaxf(redm[2], redm[3]));
  float sum = 0.f;
#pragma unroll
  for (int i = 0; i < 8; ++i) { x[i] = __expf(x[i] - m); sum += x[i]; }
#pragma unroll
  for (int o = 32; o; o >>= 1) sum += __shfl_xor(sum, o, 64);
  if ((tid & 63) == 0) reds[tid >> 6] = sum;
  __syncthreads();
  sum = reds[0] + reds[1] + reds[2] + reds[3];
  float inv = 1.0f / sum;
  uint32_t ou[4];
#pragma unroll
  for (int i = 0; i < 4; ++i) {
    uint32_t lo = f2bf(x[2 * i] * inv);
    uint32_t hi = f2bf(x[2 * i + 1] * inv);
    ou[i] = lo | (hi << 16);
  }
  reinterpret_cast<uint4*>(p)[tid] = make_uint4(ou[0], ou[1], ou[2], ou[3]);
}

// ------------------------------------------------------------------------------
extern "C" void kernel_launch(void* const* d_in, const int* in_sizes, int n_in,
                              void* d_out, int out_size, void* d_ws, size_t ws_size,
                              hipStream_t stream) {
  const float* x       = (const float*)d_in[0];
  const float* w_qk    = (const float*)d_in[1];
  const float* w_dense = (const float*)d_in[2];
  const float* b_dense = (const float*)d_in[3];
  float* out = (float*)d_out;

  const size_t NX = 4ull * 2048 * 2048;
  const size_t NW = 4096ull * 2048;
  const size_t ND = 2048ull * 2048;

  // d_ws layout (bf16): xb | wqkb | wdb | k0T | vT   (126 MB peak)
  uint16_t* xb   = (uint16_t*)d_ws;       // 8192x2048
  uint16_t* wqkb = xb + NX;               // 4096x2048
  uint16_t* wdb  = wqkb + NW;             // 2048x2048
  uint16_t* k0T  = wdb + ND;              // 2048x8192
  uint16_t* vT   = k0T + NX;              // 2048x8192
  uint16_t* qb   = xb;                    // alias: xb dead after stage A
  uint16_t* Vn   = (uint16_t*)d_out;      // 8192x2048 (dead before stage D)
  uint16_t* sb   = Vn + NX;               // (4,2048,2048)

  const float scale = (float)(1.0 / sqrt(0.5 * 2048.0 * 2047.0));

  // 0: fused fp32 -> bf16 cast (dsts contiguous: xb|wqkb|wdb)
  k_cast_all<<<dim3((NX4 + NW4 + ND4) / 256), 256, 0, stream>>>(x, w_qk, w_dense, xb);

  // A: kv^T  (M=4096 e, N=8192 bt, K=2048)
  k_gemm_kv<<<dim3(64, 32), 256, 0, stream>>>(wqkb, xb, k0T, vT);
  // T: vT -> Vn
  k_transpose<<<dim3(128, 32), 256, 0, stream>>>(vT, Vn);
  // B: s = scale * k0T @ Vn^T   (per batch 2048^3)
  k_gemm_bt<<<dim3(16, 16, 4), 256, 0, stream>>>(
      k0T, 8192, 2048L, Vn, 2048, 2048L * 2048L, sb, 2048, 2048L * 2048L, 2048, scale);
  // S: softmax rows
  k_softmax<<<dim3(8192), 256, 0, stream>>>(sb);
  // C: q = a @ vT^T             (per batch 2048^3)
  k_gemm_bt<<<dim3(16, 16, 4), 256, 0, stream>>>(
      sb, 2048, 2048L * 2048L, vT, 8192, 2048L, qb, 2048, 2048L * 2048L, 2048, 1.0f);
  // D: out = perm(q) @ w_dense^T + bias  (M=8192, N=2048, K=2048) -> fp32
  k_gemm_out<<<dim3(16, 64), 256, 0, stream>>>(qb, wdb, b_dense, out);
}

// Round 5
// 539.269 us; speedup vs baseline: 1.2089x; 1.0679x over previous
//
#include <hip/hip_runtime.h>
#include <stdint.h>
#include <math.h>

// B=4, T=2048, D=2048, HEADS=16.  Inputs/outputs fp32; internal bf16 MFMA.
//
// Pipeline: cast -> A: kv^T -> T: transpose -> B: scores -> S: softmax ->
//           C: q = a@vT^T -> D: perm(q)@w_dense^T + bias.
//
// GEMM core (this round): CK-style register double-buffer.  128x128 tile,
// BK=64, 256 thr (4 waves, 2x2 of 64x64), single-buffered 32KB LDS, prefetch
// of tile k+1 into VGPRs issued BEFORE compute of tile k and consumed (via
// ds_write) only after the next barrier — so the vmcnt wait lands one full
// compute phase after issue regardless of how conservatively the memory
// legalizer drains at barriers.  This is what the global_load_lds intrinsic
// structurally cannot express (its LDS write must drain at the next barrier).
// XOR k-chunk swizzle retained (round 3: 0 bank conflicts); write address
// simplifies to (c*32 + tid/8)*64 + (tid&7)*8 elems.

typedef __bf16 bf16x8 __attribute__((ext_vector_type(8)));
typedef float  f32x4  __attribute__((ext_vector_type(4)));

__device__ __forceinline__ float bf2f(uint16_t u) {
  union { uint32_t i; float f; } c; c.i = ((uint32_t)u) << 16; return c.f;
}
__device__ __forceinline__ uint16_t f2bf(float f) {
  union { float f; uint32_t i; } c; c.f = f;
  uint32_t i = c.i;
  return (uint16_t)((i + 0x7fffu + ((i >> 16) & 1u)) >> 16);  // RNE
}

// ---- fused fp32 -> bf16 cast over x|w_qk|w_dense -----------------------------
#define NX4 4194304u
#define NW4 2097152u
#define ND4 1048576u
__global__ __launch_bounds__(256) void k_cast_all(
    const float* __restrict__ x, const float* __restrict__ wqk,
    const float* __restrict__ wd, uint16_t* __restrict__ dst) {
  uint32_t i = blockIdx.x * 256 + threadIdx.x;
  float4 v;
  if (i < NX4)            v = reinterpret_cast<const float4*>(x)[i];
  else if (i < NX4 + NW4) v = reinterpret_cast<const float4*>(wqk)[i - NX4];
  else                    v = reinterpret_cast<const float4*>(wd)[i - NX4 - NW4];
  ushort4 o;
  o.x = f2bf(v.x); o.y = f2bf(v.y); o.z = f2bf(v.z); o.w = f2bf(v.w);
  reinterpret_cast<ushort4*>(dst)[i] = o;
}

// staging-pointer helper: chunk c of a row-major operand (swizzled k-offset)
__device__ __forceinline__ const uint16_t* stage_ptr(
    const uint16_t* base, int tile_row0, int c, int lda) {
  const int tid = threadIdx.x;
  const int r3 = tid >> 3;
  const int ko = (((tid & 7) ^ (r3 & 7)) * 8);
  return base + (size_t)(tile_row0 + c * 32 + r3) * lda + ko;
}

// ---- register-dbuf 128x128 GEMM core, BK=64, LDS 2x16KB (As/Bs) -------------
__device__ __forceinline__ void gemm_core_reg(
    const uint16_t* a0, const uint16_t* a1, const uint16_t* a2, const uint16_t* a3,
    const uint16_t* b0, const uint16_t* b1, const uint16_t* b2, const uint16_t* b3,
    uint16_t* As, uint16_t* Bs, int K, f32x4 acc[4][4])
{
  const int tid = threadIdx.x;
  const int w = tid >> 6, l = tid & 63;
  const int wm = (w >> 1) * 64, wn = (w & 1) * 64;
  const int frow = l & 15, fkc = l >> 4;
  const int xr = frow & 7;
  const int off0 = (fkc ^ xr) * 8;
  const int off1 = ((4 + fkc) ^ xr) * 8;
  // LDS write slot (elems): row (c*32 + tid/8), position (tid&7)*8 in 64-row
  const int lw = (tid >> 3) * 64 + (tid & 7) * 8;   // + c*2048 per chunk

  uint4 ra0, ra1, ra2, ra3, rb0, rb1, rb2, rb3;
  ra0 = *reinterpret_cast<const uint4*>(a0); a0 += 64;
  ra1 = *reinterpret_cast<const uint4*>(a1); a1 += 64;
  ra2 = *reinterpret_cast<const uint4*>(a2); a2 += 64;
  ra3 = *reinterpret_cast<const uint4*>(a3); a3 += 64;
  rb0 = *reinterpret_cast<const uint4*>(b0); b0 += 64;
  rb1 = *reinterpret_cast<const uint4*>(b1); b1 += 64;
  rb2 = *reinterpret_cast<const uint4*>(b2); b2 += 64;
  rb3 = *reinterpret_cast<const uint4*>(b3); b3 += 64;

  for (int kb = 0; kb < K; kb += 64) {
    __syncthreads();   // reads of previous tile complete -> LDS reusable
    *reinterpret_cast<uint4*>(&As[lw])        = ra0;
    *reinterpret_cast<uint4*>(&As[lw + 2048]) = ra1;
    *reinterpret_cast<uint4*>(&As[lw + 4096]) = ra2;
    *reinterpret_cast<uint4*>(&As[lw + 6144]) = ra3;
    *reinterpret_cast<uint4*>(&Bs[lw])        = rb0;
    *reinterpret_cast<uint4*>(&Bs[lw + 2048]) = rb1;
    *reinterpret_cast<uint4*>(&Bs[lw + 4096]) = rb2;
    *reinterpret_cast<uint4*>(&Bs[lw + 6144]) = rb3;
    __syncthreads();   // publish tile kb
    if (kb + 64 < K) {  // prefetch tile kb+64 -> regs (in flight across compute)
      ra0 = *reinterpret_cast<const uint4*>(a0); a0 += 64;
      ra1 = *reinterpret_cast<const uint4*>(a1); a1 += 64;
      ra2 = *reinterpret_cast<const uint4*>(a2); a2 += 64;
      ra3 = *reinterpret_cast<const uint4*>(a3); a3 += 64;
      rb0 = *reinterpret_cast<const uint4*>(b0); b0 += 64;
      rb1 = *reinterpret_cast<const uint4*>(b1); b1 += 64;
      rb2 = *reinterpret_cast<const uint4*>(b2); b2 += 64;
      rb3 = *reinterpret_cast<const uint4*>(b3); b3 += 64;
    }
#pragma unroll
    for (int h = 0; h < 2; ++h) {
      const int off = h ? off1 : off0;
      bf16x8 af[4], bfv[4];
#pragma unroll
      for (int mi = 0; mi < 4; ++mi)
        af[mi] = *reinterpret_cast<const bf16x8*>(&As[(wm + mi * 16 + frow) * 64 + off]);
#pragma unroll
      for (int ni = 0; ni < 4; ++ni)
        bfv[ni] = *reinterpret_cast<const bf16x8*>(&Bs[(wn + ni * 16 + frow) * 64 + off]);
#pragma unroll
      for (int mi = 0; mi < 4; ++mi)
#pragma unroll
        for (int ni = 0; ni < 4; ++ni)
          acc[mi][ni] = __builtin_amdgcn_mfma_f32_16x16x32_bf16(af[mi], bfv[ni], acc[mi][ni], 0, 0, 0);
    }
  }
}

// ---- stage A: kv^T, block-uniform split-store into k0T / vT ------------------
__global__ __launch_bounds__(256) void k_gemm_kv(
    const uint16_t* __restrict__ W,    // wqkb 4096x2048
    const uint16_t* __restrict__ X,    // xb   8192x2048
    uint16_t* __restrict__ k0T,        // 2048x8192
    uint16_t* __restrict__ vT)         // 2048x8192
{
  __shared__ uint16_t As[8192], Bs[8192];
  const int bm = blockIdx.y, bn = blockIdx.x;
  f32x4 acc[4][4];
#pragma unroll
  for (int i = 0; i < 4; ++i)
#pragma unroll
    for (int j = 0; j < 4; ++j) acc[i][j] = (f32x4){0.f, 0.f, 0.f, 0.f};
  gemm_core_reg(stage_ptr(W, bm * 128, 0, 2048), stage_ptr(W, bm * 128, 1, 2048),
                stage_ptr(W, bm * 128, 2, 2048), stage_ptr(W, bm * 128, 3, 2048),
                stage_ptr(X, bn * 128, 0, 2048), stage_ptr(X, bn * 128, 1, 2048),
                stage_ptr(X, bn * 128, 2, 2048), stage_ptr(X, bn * 128, 3, 2048),
                As, Bs, 2048, acc);
  const int tid = threadIdx.x;
  const int w = tid >> 6, l = tid & 63;
  const int wm = (w >> 1) * 64, wn = (w & 1) * 64;
  const int cr = (l >> 4) * 4, cc = l & 15;
  uint16_t* Cb = (bm < 16) ? (k0T + (size_t)bm * 128 * 8192)
                           : (vT + (size_t)(bm - 16) * 128 * 8192);
#pragma unroll
  for (int mi = 0; mi < 4; ++mi)
#pragma unroll
    for (int ni = 0; ni < 4; ++ni)
#pragma unroll
      for (int g = 0; g < 4; ++g) {
        int lr = wm + mi * 16 + cr + g;
        int bt = bn * 128 + wn + ni * 16 + cc;
        Cb[(size_t)lr * 8192 + bt] = f2bf(acc[mi][ni][g]);
      }
}

// ---- generic batched A@B^T (both K-contig), scaled bf16 store ----------------
__global__ __launch_bounds__(256) void k_gemm_bt(
    const uint16_t* __restrict__ A, int lda, long sA,
    const uint16_t* __restrict__ B, int ldb, long sB,
    uint16_t* __restrict__ C, int ldc, long sC,
    int K, float scale)
{
  __shared__ uint16_t As[8192], Bs[8192];
  const int z = blockIdx.z;
  A += (size_t)z * sA; B += (size_t)z * sB; C += (size_t)z * sC;
  const int bm = blockIdx.y, bn = blockIdx.x;
  f32x4 acc[4][4];
#pragma unroll
  for (int i = 0; i < 4; ++i)
#pragma unroll
    for (int j = 0; j < 4; ++j) acc[i][j] = (f32x4){0.f, 0.f, 0.f, 0.f};
  gemm_core_reg(stage_ptr(A, bm * 128, 0, lda), stage_ptr(A, bm * 128, 1, lda),
                stage_ptr(A, bm * 128, 2, lda), stage_ptr(A, bm * 128, 3, lda),
                stage_ptr(B, bn * 128, 0, ldb), stage_ptr(B, bn * 128, 1, ldb),
                stage_ptr(B, bn * 128, 2, ldb), stage_ptr(B, bn * 128, 3, ldb),
                As, Bs, K, acc);
  const int tid = threadIdx.x;
  const int w = tid >> 6, l = tid & 63;
  const int wm = (w >> 1) * 64, wn = (w & 1) * 64;
  const int cr = (l >> 4) * 4, cc = l & 15;
#pragma unroll
  for (int mi = 0; mi < 4; ++mi)
#pragma unroll
    for (int ni = 0; ni < 4; ++ni)
#pragma unroll
      for (int g = 0; g < 4; ++g) {
        int grow = bm * 128 + wm + mi * 16 + cr + g;
        int gcol = bn * 128 + wn + ni * 16 + cc;
        C[(size_t)grow * ldc + gcol] = f2bf(acc[mi][ni][g] * scale);
      }
}

// ---- stage D: permuted-A GEMM + fp32 bias/store into d_out -------------------
__device__ __forceinline__ size_t qrow_off(int rr) {
  // rr = b'*2048 + t' ; q row = (b_i, i), b_i=(t'>>4)&3, i=(t'&15)*128+b'*32+(t'>>6)
  int bp = rr >> 11, tp = rr & 2047;
  int bi = (tp >> 4) & 3;
  int i  = (tp & 15) * 128 + bp * 32 + (tp >> 6);
  return ((size_t)bi * 2048 + (size_t)i) * 2048;
}

__global__ __launch_bounds__(256) void k_gemm_out(
    const uint16_t* __restrict__ Q,     // qb (4,2048,2048) bf16
    const uint16_t* __restrict__ W,     // wdb 2048x2048 bf16
    const float*    __restrict__ bias,  // b_dense fp32 (2048)
    float*          __restrict__ Out)   // d_out 8192x2048 fp32
{
  __shared__ uint16_t As[8192], Bs[8192];
  const int tid = threadIdx.x;
  const int bm = blockIdx.y, bn = blockIdx.x;
  const int r3 = tid >> 3;
  const int ko = ((tid & 7) ^ (r3 & 7)) * 8;
  const uint16_t* a0 = Q + qrow_off(bm * 128 + 0 * 32 + r3) + ko;
  const uint16_t* a1 = Q + qrow_off(bm * 128 + 1 * 32 + r3) + ko;
  const uint16_t* a2 = Q + qrow_off(bm * 128 + 2 * 32 + r3) + ko;
  const uint16_t* a3 = Q + qrow_off(bm * 128 + 3 * 32 + r3) + ko;
  f32x4 acc[4][4];
#pragma unroll
  for (int i = 0; i < 4; ++i)
#pragma unroll
    for (int j = 0; j < 4; ++j) acc[i][j] = (f32x4){0.f, 0.f, 0.f, 0.f};
  gemm_core_reg(a0, a1, a2, a3,
                stage_ptr(W, bn * 128, 0, 2048), stage_ptr(W, bn * 128, 1, 2048),
                stage_ptr(W, bn * 128, 2, 2048), stage_ptr(W, bn * 128, 3, 2048),
                As, Bs, 2048, acc);
  const int w = tid >> 6, l = tid & 63;
  const int wm = (w >> 1) * 64, wn = (w & 1) * 64;
  const int cr = (l >> 4) * 4, cc = l & 15;
#pragma unroll
  for (int mi = 0; mi < 4; ++mi)
#pragma unroll
    for (int ni = 0; ni < 4; ++ni)
#pragma unroll
      for (int g = 0; g < 4; ++g) {
        int grow = bm * 128 + wm + mi * 16 + cr + g;
        int gcol = bn * 128 + wn + ni * 16 + cc;
        Out[(size_t)grow * 2048 + gcol] = acc[mi][ni][g] + bias[gcol];
      }
}

// ---- transpose vT (2048x8192) -> Vn (8192x2048) ------------------------------
__global__ __launch_bounds__(256) void k_transpose(
    const uint16_t* __restrict__ src, uint16_t* __restrict__ dst)
{
  __shared__ uint16_t tile[64][65];
  const int tid = threadIdx.x;
  const int bx = blockIdx.x;
  const int by = blockIdx.y;
  const int cu = tid & 31, r0 = tid >> 5;
#pragma unroll
  for (int p = 0; p < 8; ++p) {
    int r = p * 8 + r0;
    uint32_t v = *reinterpret_cast<const uint32_t*>(
        &src[(size_t)(by * 64 + r) * 8192 + bx * 64 + cu * 2]);
    tile[r][cu * 2]     = (uint16_t)(v & 0xffffu);
    tile[r][cu * 2 + 1] = (uint16_t)(v >> 16);
  }
  __syncthreads();
#pragma unroll
  for (int p = 0; p < 8; ++p) {
    int r = p * 8 + r0;
    uint32_t lo = tile[cu * 2][r], hi = tile[cu * 2 + 1][r];
    *reinterpret_cast<uint32_t*>(
        &dst[(size_t)(bx * 64 + r) * 2048 + by * 64 + cu * 2]) = lo | (hi << 16);
  }
}

// ---- row softmax (bf16 in place), 1 block per row of 2048 --------------------
__global__ __launch_bounds__(256) void k_softmax(uint16_t* __restrict__ s)
{
  uint16_t* p = s + (size_t)blockIdx.x * 2048;
  const int tid = threadIdx.x;
  uint4 raw = reinterpret_cast<const uint4*>(p)[tid];
  uint32_t u[4] = {raw.x, raw.y, raw.z, raw.w};
  float x[8];
#pragma unroll
  for (int i = 0; i < 4; ++i) {
    x[2 * i]     = bf2f((uint16_t)(u[i] & 0xffffu));
    x[2 * i + 1] = bf2f((uint16_t)(u[i] >> 16));
  }
  float m = x[0];
#pragma unroll
  for (int i = 1; i < 8; ++i) m = fmaxf(m, x[i]);
#pragma unroll
  for (int o = 32; o; o >>= 1) m = fmaxf(m, __shfl_xor(m, o, 64));
  __shared__ float redm[4], reds[4];
  if ((tid & 63) == 0) redm[tid >> 6] = m;
  __syncthreads();
  m = fmaxf(fmaxf(redm[0], redm[1]), fmaxf(redm[2], redm[3]));
  float sum = 0.f;
#pragma unroll
  for (int i = 0; i < 8; ++i) { x[i] = __expf(x[i] - m); sum += x[i]; }
#pragma unroll
  for (int o = 32; o; o >>= 1) sum += __shfl_xor(sum, o, 64);
  if ((tid & 63) == 0) reds[tid >> 6] = sum;
  __syncthreads();
  sum = reds[0] + reds[1] + reds[2] + reds[3];
  float inv = 1.0f / sum;
  uint32_t ou[4];
#pragma unroll
  for (int i = 0; i < 4; ++i) {
    uint32_t lo = f2bf(x[2 * i] * inv);
    uint32_t hi = f2bf(x[2 * i + 1] * inv);
    ou[i] = lo | (hi << 16);
  }
  reinterpret_cast<uint4*>(p)[tid] = make_uint4(ou[0], ou[1], ou[2], ou[3]);
}

// ------------------------------------------------------------------------------
extern "C" void kernel_launch(void* const* d_in, const int* in_sizes, int n_in,
                              void* d_out, int out_size, void* d_ws, size_t ws_size,
                              hipStream_t stream) {
  const float* x       = (const float*)d_in[0];
  const float* w_qk    = (const float*)d_in[1];
  const float* w_dense = (const float*)d_in[2];
  const float* b_dense = (const float*)d_in[3];
  float* out = (float*)d_out;

  const size_t NX = 4ull * 2048 * 2048;
  const size_t NW = 4096ull * 2048;
  const size_t ND = 2048ull * 2048;

  // d_ws layout (bf16): xb | wqkb | wdb | k0T | vT   (126 MB peak)
  uint16_t* xb   = (uint16_t*)d_ws;
  uint16_t* wqkb = xb + NX;
  uint16_t* wdb  = wqkb + NW;
  uint16_t* k0T  = wdb + ND;
  uint16_t* vT   = k0T + NX;
  uint16_t* qb   = xb;                    // alias: xb dead after stage A
  uint16_t* Vn   = (uint16_t*)d_out;      // d_out as scratch (dead before D)
  uint16_t* sb   = Vn + NX;

  const float scale = (float)(1.0 / sqrt(0.5 * 2048.0 * 2047.0));

  k_cast_all<<<dim3((NX4 + NW4 + ND4) / 256), 256, 0, stream>>>(x, w_qk, w_dense, xb);

  // A: kv^T  (M=4096 e, N=8192 bt, K=2048)
  k_gemm_kv<<<dim3(64, 32), 256, 0, stream>>>(wqkb, xb, k0T, vT);
  // T: vT -> Vn
  k_transpose<<<dim3(128, 32), 256, 0, stream>>>(vT, Vn);
  // B: s = scale * k0T @ Vn^T
  k_gemm_bt<<<dim3(16, 16, 4), 256, 0, stream>>>(
      k0T, 8192, 2048L, Vn, 2048, 2048L * 2048L, sb, 2048, 2048L * 2048L, 2048, scale);
  // S: softmax rows
  k_softmax<<<dim3(8192), 256, 0, stream>>>(sb);
  // C: q = a @ vT^T
  k_gemm_bt<<<dim3(16, 16, 4), 256, 0, stream>>>(
      sb, 2048, 2048L * 2048L, vT, 8192, 2048L, qb, 2048, 2048L * 2048L, 2048, 1.0f);
  // D: out = perm(q) @ w_dense^T + bias -> fp32
  k_gemm_out<<<dim3(16, 64), 256, 0, stream>>>(qb, wdb, b_dense, out);
}